// Round 2
// baseline (286.272 us; speedup 1.0000x reference)
//
#include <hip/hip_runtime.h>
#include <hip/hip_bf16.h>
#include <stdint.h>

typedef __attribute__((ext_vector_type(8))) short bf16x8;
typedef __attribute__((ext_vector_type(4))) float f32x4;

static constexpr int BATCH = 2;
static constexpr int SEQ = 2048;
static constexpr int EMB = 1024;
static constexpr int NH = 16;
static constexpr int HD_ = 64;

#define AS1 __attribute__((address_space(1)))
#define AS3 __attribute__((address_space(3)))

__device__ __forceinline__ void gload_lds16(const void* g, void* l) {
  __builtin_amdgcn_global_load_lds((const AS1 uint32_t*)g, (AS3 uint32_t*)l, 16, 0, 0);
}

// ---------------- convert f32 -> bf16 hi/lo split ----------------
__global__ __launch_bounds__(256) void k_convert_split(const float* __restrict__ in,
                                                       __hip_bfloat16* __restrict__ oh,
                                                       __hip_bfloat16* __restrict__ ol,
                                                       int n4) {
  int idx = blockIdx.x * 256 + threadIdx.x;
  if (idx >= n4) return;
  float4 v = reinterpret_cast<const float4*>(in)[idx];
  const float* f = reinterpret_cast<const float*>(&v);
  __hip_bfloat16 h[4], l[4];
#pragma unroll
  for (int i = 0; i < 4; ++i) {
    h[i] = __float2bfloat16(f[i]);
    l[i] = __float2bfloat16(f[i] - __bfloat162float(h[i]));
  }
  reinterpret_cast<uint2*>(oh)[idx] = *reinterpret_cast<uint2*>(h);
  reinterpret_cast<uint2*>(ol)[idx] = *reinterpret_cast<uint2*>(l);
}

// ---------------- transpose + convert: in[R][C] f32 -> out[C][R] bf16 (opt split) ----------------
template <int SPLIT>
__global__ __launch_bounds__(256) void k_transpose(const float* __restrict__ in,
                                                   __hip_bfloat16* __restrict__ oh,
                                                   __hip_bfloat16* __restrict__ ol,
                                                   int R, int C) {
  __shared__ float tile[32][33];
  const int t = threadIdx.x;
  const int tr = t >> 5, tc = t & 31;
  const int r0 = blockIdx.y * 32, c0 = blockIdx.x * 32;
#pragma unroll
  for (int rr = 0; rr < 32; rr += 8)
    tile[tr + rr][tc] = in[(size_t)(r0 + tr + rr) * C + c0 + tc];
  __syncthreads();
#pragma unroll
  for (int rr = 0; rr < 32; rr += 8) {
    const float v = tile[tc][tr + rr];
    const __hip_bfloat16 h = __float2bfloat16(v);
    oh[(size_t)(c0 + tr + rr) * R + r0 + tc] = h;
    if constexpr (SPLIT)
      ol[(size_t)(c0 + tr + rr) * R + r0 + tc] =
          __float2bfloat16(v - __bfloat162float(h));
  }
}

// ---------------- 128x128 bf16 GEMM (A[M][K] * Bt[N][K]^T) ----------------
// SPLIT: A/B given as hi/lo pairs; acc = aH*bH + aH*bL + aL*bH
// MODE 0: QKV epilogue -> scatter q(hi/lo, x8), k(hi/lo), v^T(bf16)
// MODE 1: proj epilogue -> f32 out + bias
template <int MODE, int SPLIT>
__global__ __launch_bounds__(256) void k_gemm_bt(
    const __hip_bfloat16* __restrict__ Ah, const __hip_bfloat16* __restrict__ Al,
    const __hip_bfloat16* __restrict__ Bh, const __hip_bfloat16* __restrict__ Bl,
    const float* __restrict__ bias, int M, int N, int K,
    __hip_bfloat16* __restrict__ oqh, __hip_bfloat16* __restrict__ oql,
    __hip_bfloat16* __restrict__ okh, __hip_bfloat16* __restrict__ okl,
    __hip_bfloat16* __restrict__ ov, float* __restrict__ of) {
  __shared__ __hip_bfloat16 AsH[2][128 * 32];
  __shared__ __hip_bfloat16 BsH[2][128 * 32];
  __shared__ __hip_bfloat16 AsL[SPLIT ? 2 : 1][128 * 32];
  __shared__ __hip_bfloat16 BsL[SPLIT ? 2 : 1][128 * 32];
  const int t = threadIdx.x;
  const int l = t & 63, w = t >> 6;
  const int lr = l & 15, lg = l >> 4;
  const int wr = w >> 1, wc = w & 1;
  const int m0 = blockIdx.y * 128, n0 = blockIdx.x * 128;

  auto stage = [&](int buf, int k0) {
#pragma unroll
    for (int j = 0; j < 2; ++j) {
      const int c = t + 256 * j;
      const int row = c >> 2, cb = c & 3;
      const size_t ga = (size_t)(m0 + row) * K + k0 + cb * 8;
      const size_t gb = (size_t)(n0 + row) * K + k0 + cb * 8;
      gload_lds16(Ah + ga, &AsH[buf][c * 8]);
      gload_lds16(Bh + gb, &BsH[buf][c * 8]);
      if constexpr (SPLIT) {
        gload_lds16(Al + ga, &AsL[buf][c * 8]);
        gload_lds16(Bl + gb, &BsL[buf][c * 8]);
      }
    }
  };

  f32x4 acc[4][4];
#pragma unroll
  for (int m = 0; m < 4; ++m)
#pragma unroll
    for (int n = 0; n < 4; ++n) acc[m][n] = f32x4{0.f, 0.f, 0.f, 0.f};

  stage(0, 0);
  const int NT = K / 32;
  int cur = 0;
  for (int kt = 0; kt < NT; ++kt) {
    __syncthreads();
    if (kt + 1 < NT) stage(cur ^ 1, (kt + 1) * 32);
    bf16x8 afh[4], bfh[4], afl[4], bfl[4];
#pragma unroll
    for (int m = 0; m < 4; ++m) {
      const int off = (wr * 64 + m * 16 + lr) * 32 + lg * 8;
      afh[m] = *(const bf16x8*)&AsH[cur][off];
      if constexpr (SPLIT) afl[m] = *(const bf16x8*)&AsL[cur][off];
    }
#pragma unroll
    for (int n = 0; n < 4; ++n) {
      const int off = (wc * 64 + n * 16 + lr) * 32 + lg * 8;
      bfh[n] = *(const bf16x8*)&BsH[cur][off];
      if constexpr (SPLIT) bfl[n] = *(const bf16x8*)&BsL[cur][off];
    }
#pragma unroll
    for (int m = 0; m < 4; ++m)
#pragma unroll
      for (int n = 0; n < 4; ++n) {
        acc[m][n] =
            __builtin_amdgcn_mfma_f32_16x16x32_bf16(afh[m], bfh[n], acc[m][n], 0, 0, 0);
        if constexpr (SPLIT) {
          acc[m][n] = __builtin_amdgcn_mfma_f32_16x16x32_bf16(afh[m], bfl[n],
                                                              acc[m][n], 0, 0, 0);
          acc[m][n] = __builtin_amdgcn_mfma_f32_16x16x32_bf16(afl[m], bfh[n],
                                                              acc[m][n], 0, 0, 0);
        }
      }
    cur ^= 1;
  }

#pragma unroll
  for (int m = 0; m < 4; ++m) {
#pragma unroll
    for (int n = 0; n < 4; ++n) {
#pragma unroll
      for (int i = 0; i < 4; ++i) {
        const int row = m0 + wr * 64 + m * 16 + lg * 4 + i;
        const int col = n0 + wc * 64 + n * 16 + lr;
        const float v = acc[m][n][i] + bias[col];
        if constexpr (MODE == 0) {
          const int b = row >> 11, s = row & (SEQ - 1);
          const int h = col / 192, r = col - h * 192;
          const size_t bh = (size_t)b * NH + h;
          if (r < 64) {
            const float v8 = v * 8.0f;  // fold logit scale (exact: exponent shift)
            const __hip_bfloat16 hi = __float2bfloat16(v8);
            oqh[(bh * SEQ + s) * HD_ + r] = hi;
            oql[(bh * SEQ + s) * HD_ + r] =
                __float2bfloat16(v8 - __bfloat162float(hi));
          } else if (r < 128) {
            const __hip_bfloat16 hi = __float2bfloat16(v);
            okh[(bh * SEQ + s) * HD_ + (r - 64)] = hi;
            okl[(bh * SEQ + s) * HD_ + (r - 64)] =
                __float2bfloat16(v - __bfloat162float(hi));
          } else {
            ov[(bh * HD_ + (r - 128)) * SEQ + s] = __float2bfloat16(v);  // V^T
          }
        } else {
          of[(size_t)row * N + col] = v;
        }
      }
    }
  }
}

// ---------------- flash attention: O = softmax(QK^T) V, split-precision logits ----------------
__global__ __launch_bounds__(256) void k_attn(
    const __hip_bfloat16* __restrict__ qsh, const __hip_bfloat16* __restrict__ qsl,
    const __hip_bfloat16* __restrict__ ksh, const __hip_bfloat16* __restrict__ ksl,
    const __hip_bfloat16* __restrict__ vt, __hip_bfloat16* __restrict__ ao) {
  __shared__ __hip_bfloat16 KtH[64][72];
  __shared__ __hip_bfloat16 KtL[64][72];
  __shared__ __hip_bfloat16 Vt[64][72];
  __shared__ __hip_bfloat16 Pl[4][16][72];
  const int t = threadIdx.x;
  const int l = t & 63, w = t >> 6;
  const int lr = l & 15, lg = l >> 4;
  const int bh = blockIdx.y;
  const int qb = blockIdx.x * 64 + w * 16;

  const size_t qoff = ((size_t)bh * SEQ + qb + lr) * HD_;
  const bf16x8 aQ0h = *(const bf16x8*)(qsh + qoff + lg * 8);
  const bf16x8 aQ1h = *(const bf16x8*)(qsh + qoff + 32 + lg * 8);
  const bf16x8 aQ0l = *(const bf16x8*)(qsl + qoff + lg * 8);
  const bf16x8 aQ1l = *(const bf16x8*)(qsl + qoff + 32 + lg * 8);

  float mr[4], lsum[4];
  f32x4 oacc[4];
#pragma unroll
  for (int i = 0; i < 4; ++i) { mr[i] = -1e30f; lsum[i] = 0.f; }
#pragma unroll
  for (int n = 0; n < 4; ++n) oacc[n] = f32x4{0.f, 0.f, 0.f, 0.f};

  for (int kv0 = 0; kv0 < SEQ; kv0 += 64) {
    __syncthreads();
#pragma unroll
    for (int j = 0; j < 2; ++j) {
      const int c = t + 256 * j;
      const int row = c >> 3, cb = c & 7;
      const size_t koff = ((size_t)bh * SEQ + kv0 + row) * HD_ + cb * 8;
      *(bf16x8*)&KtH[row][cb * 8] = *(const bf16x8*)(ksh + koff);
      *(bf16x8*)&KtL[row][cb * 8] = *(const bf16x8*)(ksl + koff);
      *(bf16x8*)&Vt[row][cb * 8] =
          *(const bf16x8*)(vt + ((size_t)bh * HD_ + row) * SEQ + kv0 + cb * 8);
    }
    __syncthreads();

    // S = Q K^T in split precision: qh*kh + qh*kl + ql*kh
    f32x4 sa[4];
#pragma unroll
    for (int t4 = 0; t4 < 4; ++t4) {
      const bf16x8 bk0h = *(const bf16x8*)&KtH[t4 * 16 + lr][lg * 8];
      const bf16x8 bk1h = *(const bf16x8*)&KtH[t4 * 16 + lr][32 + lg * 8];
      const bf16x8 bk0l = *(const bf16x8*)&KtL[t4 * 16 + lr][lg * 8];
      const bf16x8 bk1l = *(const bf16x8*)&KtL[t4 * 16 + lr][32 + lg * 8];
      f32x4 s = f32x4{0.f, 0.f, 0.f, 0.f};
      s = __builtin_amdgcn_mfma_f32_16x16x32_bf16(aQ0h, bk0h, s, 0, 0, 0);
      s = __builtin_amdgcn_mfma_f32_16x16x32_bf16(aQ1h, bk1h, s, 0, 0, 0);
      s = __builtin_amdgcn_mfma_f32_16x16x32_bf16(aQ0h, bk0l, s, 0, 0, 0);
      s = __builtin_amdgcn_mfma_f32_16x16x32_bf16(aQ1h, bk1l, s, 0, 0, 0);
      s = __builtin_amdgcn_mfma_f32_16x16x32_bf16(aQ0l, bk0h, s, 0, 0, 0);
      s = __builtin_amdgcn_mfma_f32_16x16x32_bf16(aQ1l, bk1h, s, 0, 0, 0);
      sa[t4] = s;
    }

    float tmax[4], nm[4], corr[4], tsum[4];
#pragma unroll
    for (int i = 0; i < 4; ++i)
      tmax[i] = fmaxf(fmaxf(sa[0][i], sa[1][i]), fmaxf(sa[2][i], sa[3][i]));
#pragma unroll
    for (int i = 0; i < 4; ++i) {
      tmax[i] = fmaxf(tmax[i], __shfl_xor(tmax[i], 1));
      tmax[i] = fmaxf(tmax[i], __shfl_xor(tmax[i], 2));
      tmax[i] = fmaxf(tmax[i], __shfl_xor(tmax[i], 4));
      tmax[i] = fmaxf(tmax[i], __shfl_xor(tmax[i], 8));
      nm[i] = fmaxf(mr[i], tmax[i]);
      corr[i] = __expf(mr[i] - nm[i]);
      mr[i] = nm[i];
      tsum[i] = 0.f;
    }
#pragma unroll
    for (int t4 = 0; t4 < 4; ++t4) {
#pragma unroll
      for (int i = 0; i < 4; ++i) {
        const float p = __expf(sa[t4][i] - nm[i]);
        tsum[i] += p;
        Pl[w][lg * 4 + i][t4 * 16 + lr] = __float2bfloat16(p);
      }
    }
#pragma unroll
    for (int i = 0; i < 4; ++i) {
      tsum[i] += __shfl_xor(tsum[i], 1);
      tsum[i] += __shfl_xor(tsum[i], 2);
      tsum[i] += __shfl_xor(tsum[i], 4);
      tsum[i] += __shfl_xor(tsum[i], 8);
      lsum[i] = lsum[i] * corr[i] + tsum[i];
    }
#pragma unroll
    for (int n = 0; n < 4; ++n)
#pragma unroll
      for (int i = 0; i < 4; ++i) oacc[n][i] *= corr[i];

    const bf16x8 aP0 = *(const bf16x8*)&Pl[w][lr][lg * 8];
    const bf16x8 aP1 = *(const bf16x8*)&Pl[w][lr][32 + lg * 8];
#pragma unroll
    for (int n = 0; n < 4; ++n) {
      const bf16x8 bv0 = *(const bf16x8*)&Vt[n * 16 + lr][lg * 8];
      const bf16x8 bv1 = *(const bf16x8*)&Vt[n * 16 + lr][32 + lg * 8];
      oacc[n] = __builtin_amdgcn_mfma_f32_16x16x32_bf16(aP0, bv0, oacc[n], 0, 0, 0);
      oacc[n] = __builtin_amdgcn_mfma_f32_16x16x32_bf16(aP1, bv1, oacc[n], 0, 0, 0);
    }
  }

  const int b = bh >> 4, h = bh & 15;
#pragma unroll
  for (int n = 0; n < 4; ++n)
#pragma unroll
    for (int i = 0; i < 4; ++i) {
      const int row = qb + lg * 4 + i;
      const float v = oacc[n][i] / lsum[i];
      ao[((size_t)b * SEQ + row) * EMB + h * HD_ + n * 16 + lr] = __float2bfloat16(v);
    }
}

extern "C" void kernel_launch(void* const* d_in, const int* in_sizes, int n_in,
                              void* d_out, int out_size, void* d_ws, size_t ws_size,
                              hipStream_t stream) {
  const float* query = (const float*)d_in[0];
  const float* Wqkv = (const float*)d_in[3];
  const float* bqkv = (const float*)d_in[4];
  const float* Wproj = (const float*)d_in[5];
  const float* bproj = (const float*)d_in[6];
  float* out = (float*)d_out;

  char* ws = (char*)d_ws;
  const size_t MB = 1024 * 1024;
  // lifetime-aliased layout, peak 68 MB:
  __hip_bfloat16* q_hi     = (__hip_bfloat16*)(ws + 0);        // 8MB; dead after QKV GEMM
  __hip_bfloat16* q_lo     = (__hip_bfloat16*)(ws + 8 * MB);   // 8MB; dead after QKV GEMM
  __hip_bfloat16* Wqkv_th  = (__hip_bfloat16*)(ws + 16 * MB);  // 6MB
  __hip_bfloat16* Wqkv_tl  = (__hip_bfloat16*)(ws + 22 * MB);  // 6MB
  __hip_bfloat16* q_s_hi   = (__hip_bfloat16*)(ws + 28 * MB);  // 8MB
  __hip_bfloat16* q_s_lo   = (__hip_bfloat16*)(ws + 36 * MB);  // 8MB
  __hip_bfloat16* k_s_hi   = (__hip_bfloat16*)(ws + 44 * MB);  // 8MB
  __hip_bfloat16* k_s_lo   = (__hip_bfloat16*)(ws + 52 * MB);  // 8MB
  __hip_bfloat16* v_t      = (__hip_bfloat16*)(ws + 60 * MB);  // 8MB
  __hip_bfloat16* a_o      = (__hip_bfloat16*)(ws + 0);        // aliases q_hi
  __hip_bfloat16* Wproj_t  = (__hip_bfloat16*)(ws + 8 * MB);   // aliases q_lo

  const int M = BATCH * SEQ;  // 4096
  k_convert_split<<<(M * EMB / 4 + 255) / 256, 256, 0, stream>>>(query, q_hi, q_lo,
                                                                 M * EMB / 4);
  k_transpose<1><<<dim3(3 * EMB / 32, EMB / 32), 256, 0, stream>>>(Wqkv, Wqkv_th,
                                                                   Wqkv_tl, EMB, 3 * EMB);
  k_gemm_bt<0, 1><<<dim3(3 * EMB / 128, M / 128), 256, 0, stream>>>(
      q_hi, q_lo, Wqkv_th, Wqkv_tl, bqkv, M, 3 * EMB, EMB, q_s_hi, q_s_lo, k_s_hi,
      k_s_lo, v_t, nullptr);
  k_transpose<0><<<dim3(EMB / 32, EMB / 32), 256, 0, stream>>>(Wproj, Wproj_t, nullptr,
                                                               EMB, EMB);
  k_attn<<<dim3(SEQ / 64, BATCH * NH), 256, 0, stream>>>(q_s_hi, q_s_lo, k_s_hi, k_s_lo,
                                                         v_t, a_o);
  k_gemm_bt<1, 0><<<dim3(EMB / 128, M / 128), 256, 0, stream>>>(
      a_o, nullptr, Wproj_t, nullptr, bproj, M, EMB, EMB, nullptr, nullptr, nullptr,
      nullptr, nullptr, out);
}

// Round 3
// 201.598 us; speedup vs baseline: 1.4200x; 1.4200x over previous
//
#include <hip/hip_runtime.h>
#include <hip/hip_bf16.h>
#include <stdint.h>

typedef __attribute__((ext_vector_type(8))) short bf16x8;
typedef __attribute__((ext_vector_type(8))) _Float16 f16x8;
typedef __attribute__((ext_vector_type(4))) _Float16 f16x4;
typedef __attribute__((ext_vector_type(4))) float f32x4;

static constexpr int BATCH = 2;
static constexpr int SEQ = 2048;
static constexpr int EMB = 1024;
static constexpr int NH = 16;
static constexpr int HD_ = 64;

#define AS1 __attribute__((address_space(1)))
#define AS3 __attribute__((address_space(3)))

__device__ __forceinline__ void gload_lds16(const void* g, void* l) {
  __builtin_amdgcn_global_load_lds((const AS1 uint32_t*)g, (AS3 uint32_t*)l, 16, 0, 0);
}

__device__ __forceinline__ f32x4 mfma16(bf16x8 a, bf16x8 b, f32x4 c) {
  return __builtin_amdgcn_mfma_f32_16x16x32_bf16(a, b, c, 0, 0, 0);
}
__device__ __forceinline__ f32x4 mfma16(f16x8 a, f16x8 b, f32x4 c) {
  return __builtin_amdgcn_mfma_f32_16x16x32_f16(a, b, c, 0, 0, 0);
}

template <int MODE> struct elem_of { using t = __hip_bfloat16; };
template <> struct elem_of<1> { using t = _Float16; };
template <typename E> struct v8t;
template <> struct v8t<__hip_bfloat16> { using t = bf16x8; };
template <> struct v8t<_Float16> { using t = f16x8; };

// ---------------- convert f32 -> bf16 hi/lo split ----------------
__global__ __launch_bounds__(256) void k_convert_split(const float* __restrict__ in,
                                                       __hip_bfloat16* __restrict__ oh,
                                                       __hip_bfloat16* __restrict__ ol,
                                                       int n4) {
  int idx = blockIdx.x * 256 + threadIdx.x;
  if (idx >= n4) return;
  float4 v = reinterpret_cast<const float4*>(in)[idx];
  const float* f = reinterpret_cast<const float*>(&v);
  __hip_bfloat16 h[4], l[4];
#pragma unroll
  for (int i = 0; i < 4; ++i) {
    h[i] = __float2bfloat16(f[i]);
    l[i] = __float2bfloat16(f[i] - __bfloat162float(h[i]));
  }
  reinterpret_cast<uint2*>(oh)[idx] = *reinterpret_cast<uint2*>(h);
  reinterpret_cast<uint2*>(ol)[idx] = *reinterpret_cast<uint2*>(l);
}

// ---------------- transpose+convert ----------------
// TM 0: Wqkv -> bf16 hi/lo, rows permuted to [q(1024) | k(1024) | v(1024)]
// TM 1: Wproj -> f16 single, no perm
template <int TM>
__global__ __launch_bounds__(256) void k_transpose(const float* __restrict__ in,
                                                   void* __restrict__ oh_,
                                                   void* __restrict__ ol_, int R, int C) {
  __shared__ float tile[32][33];
  const int t = threadIdx.x;
  const int tr = t >> 5, tc = t & 31;
  const int r0 = blockIdx.y * 32, c0 = blockIdx.x * 32;
#pragma unroll
  for (int rr = 0; rr < 32; rr += 8)
    tile[tr + rr][tc] = in[(size_t)(r0 + tr + rr) * C + c0 + tc];
  __syncthreads();
#pragma unroll
  for (int rr = 0; rr < 32; rr += 8) {
    const int c = c0 + tr + rr;
    const float v = tile[tc][tr + rr];
    if constexpr (TM == 0) {
      const int h = c / 192, r = c - h * 192;
      const int d = (r < 64) ? h * 64 + r
                             : (r < 128 ? 1024 + h * 64 + (r - 64)
                                        : 2048 + h * 64 + (r - 128));
      const __hip_bfloat16 hi = __float2bfloat16(v);
      ((__hip_bfloat16*)oh_)[(size_t)d * R + r0 + tc] = hi;
      ((__hip_bfloat16*)ol_)[(size_t)d * R + r0 + tc] =
          __float2bfloat16(v - __bfloat162float(hi));
    } else {
      ((_Float16*)oh_)[(size_t)c * R + r0 + tc] = (_Float16)v;
    }
  }
}

// ---------------- 128x128 GEMM (A[M][K] * Bt[N][K]^T) ----------------
// MODE 0 (bf16, SPLIT=1): QK epilogue -> q_s f16 (x8), k_s f16
// MODE 2 (bf16, SPLIT=0): V epilogue -> v_t f16 transposed
// MODE 1 (f16,  SPLIT=0): proj epilogue -> f32 + bias
template <int MODE, int SPLIT>
__global__ __launch_bounds__(256) void k_gemm(
    const void* __restrict__ Ah_, const void* __restrict__ Al_,
    const void* __restrict__ Bh_, const void* __restrict__ Bl_,
    const float* __restrict__ bias, int M, int N, int K, void* __restrict__ o1_,
    void* __restrict__ o2_, float* __restrict__ of) {
  using E = typename elem_of<MODE>::t;
  using V8 = typename v8t<E>::t;
  const E* Ah = (const E*)Ah_;
  const E* Al = (const E*)Al_;
  const E* Bh = (const E*)Bh_;
  const E* Bl = (const E*)Bl_;
  __shared__ E AsH[2][128 * 32];
  __shared__ E BsH[2][128 * 32];
  __shared__ E AsL[SPLIT ? 2 : 1][128 * 32];
  __shared__ E BsL[SPLIT ? 2 : 1][128 * 32];
  const int t = threadIdx.x;
  const int l = t & 63, w = t >> 6;
  const int lr = l & 15, lg = l >> 4;
  const int wr = w >> 1, wc = w & 1;
  const int m0 = blockIdx.y * 128, n0 = blockIdx.x * 128;

  auto stage = [&](int buf, int k0) {
#pragma unroll
    for (int j = 0; j < 2; ++j) {
      const int c = t + 256 * j;
      const int row = c >> 2, cb = c & 3;
      const size_t ga = (size_t)(m0 + row) * K + k0 + cb * 8;
      const size_t gb = (size_t)(n0 + row) * K + k0 + cb * 8;
      gload_lds16(Ah + ga, &AsH[buf][c * 8]);
      gload_lds16(Bh + gb, &BsH[buf][c * 8]);
      if constexpr (SPLIT) {
        gload_lds16(Al + ga, &AsL[buf][c * 8]);
        gload_lds16(Bl + gb, &BsL[buf][c * 8]);
      }
    }
  };

  f32x4 acc[4][4];
#pragma unroll
  for (int m = 0; m < 4; ++m)
#pragma unroll
    for (int n = 0; n < 4; ++n) acc[m][n] = f32x4{0.f, 0.f, 0.f, 0.f};

  stage(0, 0);
  const int NT = K / 32;
  int cur = 0;
  for (int kt = 0; kt < NT; ++kt) {
    __syncthreads();
    if (kt + 1 < NT) stage(cur ^ 1, (kt + 1) * 32);
    V8 afh[4], bfh[4], afl[4], bfl[4];
#pragma unroll
    for (int m = 0; m < 4; ++m) {
      const int off = (wr * 64 + m * 16 + lr) * 32 + lg * 8;
      afh[m] = *(const V8*)&AsH[cur][off];
      if constexpr (SPLIT) afl[m] = *(const V8*)&AsL[cur][off];
    }
#pragma unroll
    for (int n = 0; n < 4; ++n) {
      const int off = (wc * 64 + n * 16 + lr) * 32 + lg * 8;
      bfh[n] = *(const V8*)&BsH[cur][off];
      if constexpr (SPLIT) bfl[n] = *(const V8*)&BsL[cur][off];
    }
#pragma unroll
    for (int m = 0; m < 4; ++m)
#pragma unroll
      for (int n = 0; n < 4; ++n) {
        acc[m][n] = mfma16(afh[m], bfh[n], acc[m][n]);
        if constexpr (SPLIT) {
          acc[m][n] = mfma16(afh[m], bfl[n], acc[m][n]);
          acc[m][n] = mfma16(afl[m], bfh[n], acc[m][n]);
        }
      }
    cur ^= 1;
  }

#pragma unroll
  for (int m = 0; m < 4; ++m) {
#pragma unroll
    for (int n = 0; n < 4; ++n) {
#pragma unroll
      for (int i = 0; i < 4; ++i) {
        const int row = m0 + wr * 64 + m * 16 + lg * 4 + i;
        const int col = n0 + wc * 64 + n * 16 + lr;
        if constexpr (MODE == 0) {
          // cols [0,1024)=q, [1024,2048)=k (permuted W); bias remap to original
          const int cc = col & 1023;
          const int h = cc >> 6, r = cc & 63;
          const float bv = bias[h * 192 + (col < 1024 ? 0 : 64) + r];
          const float v = acc[m][n][i] + bv;
          const int b = row >> 11, s = row & (SEQ - 1);
          const size_t dst = (((size_t)b * NH + h) * SEQ + s) * HD_ + r;
          if (col < 1024)
            ((_Float16*)o1_)[dst] = (_Float16)(v * 8.0f);  // q, scale folded
          else
            ((_Float16*)o2_)[dst] = (_Float16)v;  // k
        } else if constexpr (MODE == 2) {
          const int h = col >> 6, r = col & 63;
          const float v = acc[m][n][i] + bias[h * 192 + 128 + r];
          const int b = row >> 11, s = row & (SEQ - 1);
          ((_Float16*)o1_)[(((size_t)b * NH + h) * HD_ + r) * SEQ + s] = (_Float16)v;
        } else {
          of[(size_t)row * N + col] = acc[m][n][i] + bias[col];
        }
      }
    }
  }
}

// ---------------- flash attention, all-f16 operands, swapped QK^T ----------------
// qs: [BH][S][64] f16 (x8 folded); ks: [BH][S][64] f16; vt: [BH][64][S] f16
// ao: [B][S][E] f16
__global__ __launch_bounds__(256) void k_attn(const _Float16* __restrict__ qs,
                                              const _Float16* __restrict__ ks,
                                              const _Float16* __restrict__ vt,
                                              _Float16* __restrict__ ao) {
  __shared__ _Float16 KtF[64][72];   // [kv][d], +8 pad -> uniform b128 phases
  __shared__ _Float16 Vt[64][72];    // [d][kv]
  __shared__ _Float16 Pl[4][16][72]; // per-wave P: [q][kv]
  const int t = threadIdx.x;
  const int l = t & 63, w = t >> 6;
  const int lr = l & 15, lg = l >> 4;
  const int bh = blockIdx.y;
  const int qb = blockIdx.x * 64 + w * 16;

  // Q fragments (B-operand: n=q=lr, k=d)
  const size_t qoff = ((size_t)bh * SEQ + qb + lr) * HD_;
  const f16x8 qf0 = *(const f16x8*)(qs + qoff + lg * 8);
  const f16x8 qf1 = *(const f16x8*)(qs + qoff + 32 + lg * 8);

  float mr = -1e30f, lsum = 0.f;
  f32x4 oacc[4];
#pragma unroll
  for (int n = 0; n < 4; ++n) oacc[n] = f32x4{0.f, 0.f, 0.f, 0.f};

  for (int kv0 = 0; kv0 < SEQ; kv0 += 64) {
    __syncthreads();
#pragma unroll
    for (int j = 0; j < 2; ++j) {
      const int c = t + 256 * j;
      const int row = c >> 3, cb = c & 7;
      *(f16x8*)&KtF[row][cb * 8] =
          *(const f16x8*)(ks + ((size_t)bh * SEQ + kv0 + row) * HD_ + cb * 8);
      *(f16x8*)&Vt[row][cb * 8] =
          *(const f16x8*)(vt + ((size_t)bh * HD_ + row) * SEQ + kv0 + cb * 8);
    }
    __syncthreads();

    // S^T = K Q^T : lane holds S[kv=16*t4+4*lg+i][q=lr]
    f32x4 sa[4];
#pragma unroll
    for (int t4 = 0; t4 < 4; ++t4) {
      const f16x8 kf0 = *(const f16x8*)&KtF[t4 * 16 + lr][lg * 8];
      const f16x8 kf1 = *(const f16x8*)&KtF[t4 * 16 + lr][32 + lg * 8];
      f32x4 s = mfma16(kf0, qf0, f32x4{0.f, 0.f, 0.f, 0.f});
      sa[t4] = mfma16(kf1, qf1, s);
    }

    // online softmax: per-lane q-row; reduce over lg groups only
    float tm = sa[0][0];
#pragma unroll
    for (int t4 = 0; t4 < 4; ++t4)
#pragma unroll
      for (int i = 0; i < 4; ++i) tm = fmaxf(tm, sa[t4][i]);
    tm = fmaxf(tm, __shfl_xor(tm, 16));
    tm = fmaxf(tm, __shfl_xor(tm, 32));
    const float nm = fmaxf(mr, tm);
    const float corr = __expf(mr - nm);
    mr = nm;

    float ts = 0.f;
#pragma unroll
    for (int t4 = 0; t4 < 4; ++t4) {
      f16x4 pp;
#pragma unroll
      for (int i = 0; i < 4; ++i) {
        const float p = __expf(sa[t4][i] - nm);
        ts += p;
        pp[i] = (_Float16)p;
      }
      *(f16x4*)&Pl[w][lr][t4 * 16 + lg * 4] = pp;  // vectorized b64, bank-uniform
    }
    ts += __shfl_xor(ts, 16);
    ts += __shfl_xor(ts, 32);
    lsum = lsum * corr + ts;

    // broadcast corr to PV output layout (q = 4*lg+i)
    float cb4[4];
#pragma unroll
    for (int i = 0; i < 4; ++i)
      cb4[i] = __shfl(corr, (l & 48) + ((l >> 4) << 2) + i);
#pragma unroll
    for (int n = 0; n < 4; ++n)
#pragma unroll
      for (int i = 0; i < 4; ++i) oacc[n][i] *= cb4[i];

    // O += P V (A=P[q][kv], B=V^T[d][kv])
    const f16x8 aP0 = *(const f16x8*)&Pl[w][lr][lg * 8];
    const f16x8 aP1 = *(const f16x8*)&Pl[w][lr][32 + lg * 8];
#pragma unroll
    for (int n = 0; n < 4; ++n) {
      const f16x8 bv0 = *(const f16x8*)&Vt[n * 16 + lr][lg * 8];
      const f16x8 bv1 = *(const f16x8*)&Vt[n * 16 + lr][32 + lg * 8];
      oacc[n] = mfma16(aP0, bv0, oacc[n]);
      oacc[n] = mfma16(aP1, bv1, oacc[n]);
    }
  }

  // epilogue: fetch lsum for q=4*lg+i, normalize, store f16
  float ls4[4];
#pragma unroll
  for (int i = 0; i < 4; ++i)
    ls4[i] = __shfl(lsum, (l & 48) + ((l >> 4) << 2) + i);
  const int b = bh >> 4, h = bh & 15;
#pragma unroll
  for (int n = 0; n < 4; ++n)
#pragma unroll
    for (int i = 0; i < 4; ++i) {
      const int row = qb + ((l >> 4) << 2) + i;
      ao[((size_t)b * SEQ + row) * EMB + h * HD_ + n * 16 + lr] =
          (_Float16)(oacc[n][i] / ls4[i]);
    }
}

extern "C" void kernel_launch(void* const* d_in, const int* in_sizes, int n_in,
                              void* d_out, int out_size, void* d_ws, size_t ws_size,
                              hipStream_t stream) {
  const float* query = (const float*)d_in[0];
  const float* Wqkv = (const float*)d_in[3];
  const float* bqkv = (const float*)d_in[4];
  const float* Wproj = (const float*)d_in[5];
  const float* bproj = (const float*)d_in[6];
  float* out = (float*)d_out;

  char* ws = (char*)d_ws;
  const size_t MB = 1024 * 1024;
  __hip_bfloat16* q_hi    = (__hip_bfloat16*)(ws + 0);        // 8MB; dead after QKV GEMMs
  __hip_bfloat16* q_lo    = (__hip_bfloat16*)(ws + 8 * MB);   // 8MB; dead after QK GEMM
  __hip_bfloat16* Wqkv_th = (__hip_bfloat16*)(ws + 16 * MB);  // 6MB (rows: q|k|v)
  __hip_bfloat16* Wqkv_tl = (__hip_bfloat16*)(ws + 22 * MB);  // 6MB
  _Float16* q_s           = (_Float16*)(ws + 28 * MB);        // 8MB [32][2048][64], x8
  _Float16* k_s           = (_Float16*)(ws + 36 * MB);        // 8MB
  _Float16* v_t           = (_Float16*)(ws + 44 * MB);        // 8MB [32][64][2048]
  _Float16* a_o           = (_Float16*)(ws + 0);              // aliases q_hi
  _Float16* Wproj_t       = (_Float16*)(ws + 8 * MB);         // aliases q_lo

  const int M = BATCH * SEQ;  // 4096
  k_convert_split<<<(M * EMB / 4 + 255) / 256, 256, 0, stream>>>(query, q_hi, q_lo,
                                                                 M * EMB / 4);
  k_transpose<0><<<dim3(3 * EMB / 32, EMB / 32), 256, 0, stream>>>(Wqkv, Wqkv_th,
                                                                   Wqkv_tl, EMB, 3 * EMB);
  // q,k columns: split-bf16 precision (3 MFMA)
  k_gemm<0, 1><<<dim3(16, M / 128), 256, 0, stream>>>(
      q_hi, q_lo, Wqkv_th, Wqkv_tl, bqkv, M, 2048, EMB, q_s, k_s, nullptr);
  // v columns: single bf16 (1 MFMA)
  k_gemm<2, 0><<<dim3(8, M / 128), 256, 0, stream>>>(
      q_hi, nullptr, Wqkv_th + (size_t)2048 * EMB, nullptr, bqkv, M, 1024, EMB, v_t,
      nullptr, nullptr);
  k_transpose<1><<<dim3(EMB / 32, EMB / 32), 256, 0, stream>>>(Wproj, Wproj_t, nullptr,
                                                               EMB, EMB);
  k_attn<<<dim3(SEQ / 64, BATCH * NH), 256, 0, stream>>>(q_s, k_s, v_t, a_o);
  k_gemm<1, 0><<<dim3(EMB / 128, M / 128), 256, 0, stream>>>(
      a_o, nullptr, Wproj_t, nullptr, bproj, M, EMB, EMB, nullptr, nullptr, out);
}